// Round 4
// baseline (695.165 us; speedup 1.0000x reference)
//
#include <hip/hip_runtime.h>
#include <hip/hip_bf16.h>

// Problem dims
// B=4, T=4096 -> BT=16384 tokens; D=4096; G=1, C=4, K=128, I=4 (I2=2), M=32
// Fused GEMM: [16384 x 4096] x [4096 x 640]  (640 = 512 hidden + 128 dd)
// GEMM tiling: BM=128, BN=160 -> grid 128x4 = 512 blocks = exactly 2/CU (zero tail)

typedef _Float16 half8 __attribute__((ext_vector_type(8)));
typedef float f32x4 __attribute__((ext_vector_type(4)));

#define BT_TOK 16384
#define DDIM   4096

// output offsets (floats) in return order
static constexpr int OFF_PRE_QW1  = 0;
static constexpr int OFF_PRE_QW2  = 1048576;
static constexpr int OFF_PRE_KW1  = 2097152;
static constexpr int OFF_PRE_KW2  = 3145728;
static constexpr int OFF_PRE_QDD  = 4194304;
static constexpr int OFF_PRE_KDD  = 4718592;
static constexpr int OFF_POST_QW1 = 5242880;
static constexpr int OFF_POST_QW2 = 6291456;
static constexpr int OFF_POST_KW1 = 7340032;
static constexpr int OFF_POST_KW2 = 8388608;
static constexpr int OFF_POST_QDD = 9437184;
static constexpr int OFF_POST_KDD = 9961472;
static constexpr int OFF_KW       = 10485760;

typedef __attribute__((address_space(3))) void lds_void;
typedef const __attribute__((address_space(1))) void gbl_void;

__device__ __forceinline__ void gload16(const void* g, void* l) {
  // async global->LDS, 16B per lane; LDS dest is wave-uniform base + lane*16
  __builtin_amdgcn_global_load_lds((gbl_void*)g, (lds_void*)l, 16, 0, 0);
}

// ---------------------------------------------------------------------------
// Kernel 1a: query_vec f32 -> fp16 (A matrix), vectorized 8 elems/thread/iter
__global__ __launch_bounds__(256) void convert_a(const float* __restrict__ q,
                                                 _Float16* __restrict__ a) {
  const int stride = gridDim.x * blockDim.x;
  for (int i = blockIdx.x * blockDim.x + threadIdx.x; i < (BT_TOK * DDIM) / 8;
       i += stride) {
    const float4* p = (const float4*)(q + (size_t)i * 8);
    float4 x = p[0], y = p[1];
    half8 h;
    h[0] = (_Float16)x.x; h[1] = (_Float16)x.y;
    h[2] = (_Float16)x.z; h[3] = (_Float16)x.w;
    h[4] = (_Float16)y.x; h[5] = (_Float16)y.y;
    h[6] = (_Float16)y.z; h[7] = (_Float16)y.w;
    *(half8*)(a + (size_t)i * 8) = h;
  }
}

// ---------------------------------------------------------------------------
// Kernel 1b: build B^T fp16 [640][4096] from dw1 [4096][512] and dd_w [4096][128]
__global__ __launch_bounds__(256) void build_bt(const float* __restrict__ dw1,
                                                const float* __restrict__ ddw,
                                                _Float16* __restrict__ Bt) {
  __shared__ float tile[64][65];
  const int bn = blockIdx.x % 10, bd = blockIdx.x / 10;
  const int n0 = bn * 64, d0 = bd * 64;
  const int tid = threadIdx.x;
  const int ln = tid & 63;  // lane along contiguous dim
  const int rr = tid >> 6;  // 0..3
#pragma unroll
  for (int i = 0; i < 16; ++i) {
    int dl = rr + i * 4;  // 0..63
    int d = d0 + dl, n = n0 + ln;
    float v = (n < 512) ? dw1[d * 512 + n] : ddw[d * 128 + (n - 512)];
    tile[dl][ln] = v;
  }
  __syncthreads();
#pragma unroll
  for (int i = 0; i < 16; ++i) {
    int nl = rr + i * 4;
    Bt[(size_t)(n0 + nl) * DDIM + d0 + ln] = (_Float16)tile[ln][nl];
  }
}

// ---------------------------------------------------------------------------
// Kernel 1c: qkwT[c][n][k] fp16 from qkw flat [c][k][n], LDS transpose,
// coalesced on both global sides.
__global__ __launch_bounds__(256) void build_qkwT(const float* __restrict__ qkw,
                                                  _Float16* __restrict__ qT) {
  __shared__ float t[128][129];
  const int c = blockIdx.x;
  const float* src = qkw + c * 16384;
  for (int z = threadIdx.x; z < 16384; z += 256) {
    int k = z >> 7, n = z & 127;
    t[k][n] = src[z];  // coalesced read
  }
  __syncthreads();
  for (int z = threadIdx.x; z < 16384; z += 256) {
    int n = z >> 7, k = z & 127;
    qT[c * 16384 + z] = (_Float16)t[k][n];  // coalesced write
  }
}

// ---------------------------------------------------------------------------
// Kernel 2: main GEMM 16384x4096x640 fp16 MFMA, 128x160 tile, BK=64,
// double-buffered (stage(next) before compute(cur), one barrier/iter).
// grid 512 = 2 blocks/CU exactly, zero dispatch tail.
// Epilogue: col<512 -> gelu(exact) -> Hg fp16 [16384][512]
//           col>=512 -> tanh -> dd outputs (f32) directly to d_out.
__global__ __launch_bounds__(256) void gemm_main(const _Float16* __restrict__ A,
                                                 const _Float16* __restrict__ Bt,
                                                 _Float16* __restrict__ Hg,
                                                 float* __restrict__ out) {
  __shared__ _Float16 As[2][8192];   // [buf][128 rows][8 kslots of 8], XOR-swizzled
  __shared__ _Float16 Bs[2][10240];  // [buf][160 rows][8 kslots of 8]

  // XCD-bijective swizzle (grid 512 = 8*64); 4 consecutive wg in an XCD share
  // the A-panel (mtile) across all 4 ntiles -> L2 locality.
  int wg = (int)blockIdx.x;
  wg = (wg & 7) * 64 + (wg >> 3);
  const int mtile = wg >> 2, ntile = wg & 3;
  const int m0 = mtile << 7, n0 = ntile * 160;

  const int tid = threadIdx.x;
  const int wave = tid >> 6, lane = tid & 63;
  const int lq = lane >> 4, lc = lane & 15;

  // staging: 16B-slots; slot s -> row=s>>3, kslot=s&7.
  // LDS written LINEARLY (gload_lds rule); global source pre-swizzled:
  // gslot = (s&7) ^ (row&7); read back with kslot = kb ^ (row&7).  [rule #21]
  int aoff[4], boff[5], lbA[4], lbB[5];
#pragma unroll
  for (int j = 0; j < 5; ++j) {
    int slot = j * 256 + wave * 64 + lane;
    int row = slot >> 3;
    int gs = (slot & 7) ^ (row & 7);
    if (j < 4) {
      aoff[j] = (m0 + row) * DDIM + gs * 8;
      lbA[j] = j * 2048 + wave * 512;  // wave-uniform LDS base (halves)
    }
    boff[j] = (n0 + row) * DDIM + gs * 8;
    lbB[j] = j * 2048 + wave * 512;
  }
  const int wm = (wave >> 1) << 6;  // 0 / 64
  const int wn = (wave & 1) * 80;   // 0 / 80

  f32x4 acc[4][5];
#pragma unroll
  for (int i = 0; i < 4; ++i)
#pragma unroll
    for (int j = 0; j < 5; ++j) acc[i][j] = f32x4{0.f, 0.f, 0.f, 0.f};

  auto stage = [&](int b, int k0) {
#pragma unroll
    for (int j = 0; j < 4; ++j) gload16(A + aoff[j] + k0, &As[b][lbA[j]]);
#pragma unroll
    for (int j = 0; j < 5; ++j) gload16(Bt + boff[j] + k0, &Bs[b][lbB[j]]);
  };

  auto compute = [&](int b) {
#pragma unroll
    for (int kk = 0; kk < 2; ++kk) {
      half8 af[4], bf[5];
      const int kb = kk * 4 + lq;  // desired k-chunk
#pragma unroll
      for (int f = 0; f < 4; ++f) {
        int rowA = wm + f * 16 + lc;
        af[f] = *(const half8*)(&As[b][rowA * 64 + ((kb ^ (rowA & 7)) << 3)]);
      }
#pragma unroll
      for (int f = 0; f < 5; ++f) {
        int rowB = wn + f * 16 + lc;
        bf[f] = *(const half8*)(&Bs[b][rowB * 64 + ((kb ^ (rowB & 7)) << 3)]);
      }
      __builtin_amdgcn_s_setprio(1);
#pragma unroll
      for (int mf = 0; mf < 4; ++mf)
#pragma unroll
        for (int nf = 0; nf < 5; ++nf)
          acc[mf][nf] = __builtin_amdgcn_mfma_f32_16x16x32_f16(
              af[mf], bf[nf], acc[mf][nf], 0, 0, 0);
      __builtin_amdgcn_s_setprio(0);
    }
  };

  // prologue: fill buf0
  stage(0, 0);
  __syncthreads();
  // steady state: issue next-tile loads, compute current, barrier (drains vmcnt
  // AFTER compute -> stage latency hidden under MFMA).
  for (int t = 0; t < 63; ++t) {
    stage((t + 1) & 1, (t + 1) << 6);
    compute(t & 1);
    __syncthreads();
  }
  compute(1);  // t=63

  // Epilogue. C/D frag: col = lane&15, row = (lane>>4)*4 + reg  [m89]
  // Boundary 512 is 16-aligned -> branch is fragment-uniform.
#pragma unroll
  for (int mf = 0; mf < 4; ++mf)
#pragma unroll
    for (int nf = 0; nf < 5; ++nf) {
      int colg = n0 + wn + nf * 16 + lc;
      int row0 = m0 + wm + mf * 16 + lq * 4;
      if (colg < 512) {
#pragma unroll
        for (int r = 0; r < 4; ++r) {
          float v = acc[mf][nf][r];
          float g = 0.5f * v * (1.0f + erff(v * 0.70710678118654752f));
          Hg[(size_t)(row0 + r) * 512 + colg] = (_Float16)g;
        }
      } else {
        int j = colg - 512;  // 0..127
        int t = j >> 5;      // 0:pre_qdd 1:pre_kdd 2:post_qdd 3:post_kdd
        int base = (t & 2) ? ((t & 1) ? OFF_POST_KDD : OFF_POST_QDD)
                           : ((t & 1) ? OFF_PRE_KDD : OFF_PRE_QDD);
#pragma unroll
        for (int r = 0; r < 4; ++r)
          out[base + (row0 + r) * 32 + (j & 31)] = tanhf(acc[mf][nf][r]);
      }
    }
}

// ---------------------------------------------------------------------------
// Kernel 3: per-token epilogue. 16 tokens/block, wave w owns c-slot w.
// Hg tile LDS-staged with coalesced loads; w = h x qkw via MFMA; rmsnorm(w1);
// KW outer products with float4 stores + broadcast-friendly LDS reads.
__global__ __launch_bounds__(256) void epilogue_k(const _Float16* __restrict__ Hg,
                                                  const _Float16* __restrict__ qT,
                                                  float* __restrict__ out) {
  __shared__ _Float16 hga[16][520];      // Hg tile, +8 pad -> conflict-free reads
  __shared__ float stash[2][4][16][32];  // [pre/post][i][tok][m]  (c=1,3 waves)
  __shared__ float ddl[2][16][32];       // [pre/post][tok][m] kdd
  const int tid = threadIdx.x;
  const int wave = tid >> 6, lane = tid & 63;
  const int lq = lane >> 4, lc = lane & 15;
  const int tok0 = blockIdx.x * 16;
  const int c = wave;  // 0:pre_q 1:pre_k 2:post_q 3:post_k

  // cooperative Hg tile load: 16 rows x 1KB, fully coalesced
#pragma unroll
  for (int z = 0; z < 4; ++z) {
    int flat = z * 256 + tid;       // 0..1023 16B-slots
    int row = flat >> 6, c16 = flat & 63;
    *(half8*)(&hga[row][c16 * 8]) =
        *(const half8*)(Hg + (size_t)(tok0 + row) * 512 + c16 * 8);
  }

  // cooperative kdd preload (written by gemm_main)
#pragma unroll
  for (int z = 0; z < 4; ++z) {
    int idx = z * 256 + tid;  // 0..1023
    int pp = idx >> 9, tl = (idx >> 5) & 15, m = idx & 31;
    ddl[pp][tl][m] =
        out[(pp ? OFF_POST_KDD : OFF_PRE_KDD) + (tok0 + tl) * 32 + m];
  }
  __syncthreads();

  // A-frag from LDS: row = token (lc), k = lq*8 within each 32-chunk
  half8 af[4];
#pragma unroll
  for (int kf = 0; kf < 4; ++kf)
    af[kf] = *(const half8*)(&hga[lc][c * 128 + kf * 32 + lq * 8]);

  f32x4 acc[8];
#pragma unroll
  for (int nf = 0; nf < 8; ++nf) acc[nf] = f32x4{0.f, 0.f, 0.f, 0.f};
#pragma unroll
  for (int nf = 0; nf < 8; ++nf) {
    const _Float16* brow = qT + c * 16384 + (nf * 16 + lc) * 128 + lq * 8;
#pragma unroll
    for (int kf = 0; kf < 4; ++kf) {
      half8 bf = *(const half8*)(brow + kf * 32);
      acc[nf] = __builtin_amdgcn_mfma_f32_16x16x32_f16(af[kf], bf, acc[nf], 0, 0, 0);
    }
  }

  // output bases, computed arithmetically (no runtime-indexed arrays, rule #20)
  const int w1base = (c >> 1) * OFF_POST_QW1 + (c & 1) * OFF_PRE_KW1;
  const int w2base = w1base + OFF_PRE_QW2;
  const int cs = c >> 1;
  const bool isk = (c & 1);

  // acc[nf][r]: token = tok0 + lq*4 + r, n = nf*16 + lc; n = i*32 + m
#pragma unroll
  for (int i = 0; i < 4; ++i) {
    float vn0[4], vn1[4];
#pragma unroll
    for (int r = 0; r < 4; ++r) {
      vn0[r] = acc[2 * i][r];      // m = lc
      vn1[r] = acc[2 * i + 1][r];  // m = 16 + lc
    }
    if (i < 2) {  // rmsnorm over the 32 m-values (16 lanes x 2 regs)
#pragma unroll
      for (int r = 0; r < 4; ++r) {
        float ss = vn0[r] * vn0[r] + vn1[r] * vn1[r];
        ss += __shfl_xor(ss, 1);
        ss += __shfl_xor(ss, 2);
        ss += __shfl_xor(ss, 4);
        ss += __shfl_xor(ss, 8);
        float sc = rsqrtf(ss * 0.03125f + 1e-6f);
        vn0[r] *= sc;
        vn1[r] *= sc;
      }
    }
    const int basei = ((i < 2) ? w1base : w2base) + (i & 1) * 32;
#pragma unroll
    for (int r = 0; r < 4; ++r) {
      int token = tok0 + lq * 4 + r;
      out[basei + token * 64 + lc] = vn0[r];
      out[basei + token * 64 + 16 + lc] = vn1[r];
      if (isk) {
        stash[cs][i][lq * 4 + r][lc] = vn0[r];
        stash[cs][i][lq * 4 + r][16 + lc] = vn1[r];
      }
    }
  }
  __syncthreads();

  // KW[pp][tl][m][n] = sum_{i<2} w1n[i][m]*w2[i][n] + kdd[m]*delta(m,n)
  // 8192 float4 / 256 threads = 32 iters; float4 stores, broadcast LDS reads.
#pragma unroll 8
  for (int it = 0; it < 32; ++it) {
    int flat = it * 256 + tid;            // 0..8191 float4-slots
    int pp = flat >> 12, rest = flat & 4095;
    int tl = rest >> 8, mrow = (rest >> 3) & 31, n4 = (flat & 7) * 4;
    f32x4 s2 = *(const f32x4*)(&stash[pp][2][tl][n4]);  // broadcast across mrow
    f32x4 s3 = *(const f32x4*)(&stash[pp][3][tl][n4]);
    float a0 = stash[pp][0][tl][mrow];
    float a1 = stash[pp][1][tl][mrow];
    f32x4 v = a0 * s2 + a1 * s3;
    if ((mrow >> 2) == (flat & 7)) v[mrow & 3] += ddl[pp][tl][mrow];
    *(f32x4*)(&out[OFF_KW + (tok0 + tl) * 2048 + pp * 1024 + mrow * 32 + n4]) = v;
  }
}

// ---------------------------------------------------------------------------
extern "C" void kernel_launch(void* const* d_in, const int* in_sizes, int n_in,
                              void* d_out, int out_size, void* d_ws, size_t ws_size,
                              hipStream_t stream) {
  const float* q   = (const float*)d_in[0];  // [4,4096,4096]
  const float* dw1 = (const float*)d_in[1];  // [4096,1,4,128]
  const float* qkw = (const float*)d_in[2];  // [1,4,128,4,32]
  const float* ddw = (const float*)d_in[3];  // [4096,1,128]
  float* out = (float*)d_out;

  _Float16* Ah = (_Float16*)d_ws;                    // 16384*4096   (128 MiB)
  _Float16* Bt = Ah + (size_t)BT_TOK * DDIM;         // 640*4096     (5 MiB)
  _Float16* Hg = Bt + (size_t)640 * DDIM;            // 16384*512    (16 MiB)
  _Float16* qT = Hg + (size_t)BT_TOK * 512;          // 4*128*128    (128 KiB)

  convert_a<<<2048, 256, 0, stream>>>(q, Ah);
  build_bt<<<640, 256, 0, stream>>>(dw1, ddw, Bt);
  build_qkwT<<<4, 256, 0, stream>>>(qkw, qT);
  gemm_main<<<512, 256, 0, stream>>>(Ah, Bt, Hg, out);
  epilogue_k<<<1024, 256, 0, stream>>>(Hg, qT, out);
}

// Round 6
// 639.743 us; speedup vs baseline: 1.0866x; 1.0866x over previous
//
#include <hip/hip_runtime.h>
#include <hip/hip_bf16.h>

// B=4,T=4096 -> BT=16384 tokens; D=4096; C=4, K=128, I=4, M=32
// Fused GEMM: [16384 x 4096] x [4096 x 640] (512 hidden + 128 dd), then the
// per-token second GEMM / rmsnorm / KW fused into the same kernel.

typedef _Float16 half8 __attribute__((ext_vector_type(8)));
typedef float f32x4 __attribute__((ext_vector_type(4)));

#define BT_TOK 16384
#define DDIM   4096

static constexpr int OFF_PRE_QW1  = 0;
static constexpr int OFF_PRE_QW2  = 1048576;
static constexpr int OFF_PRE_KW1  = 2097152;
static constexpr int OFF_PRE_KW2  = 3145728;
static constexpr int OFF_PRE_QDD  = 4194304;
static constexpr int OFF_PRE_KDD  = 4718592;
static constexpr int OFF_POST_QW1 = 5242880;
static constexpr int OFF_POST_QW2 = 6291456;
static constexpr int OFF_POST_KW1 = 7340032;
static constexpr int OFF_POST_KW2 = 8388608;
static constexpr int OFF_POST_QDD = 9437184;
static constexpr int OFF_POST_KDD = 9961472;
static constexpr int OFF_KW       = 10485760;

typedef __attribute__((address_space(3))) void lds_void;
typedef const __attribute__((address_space(1))) void gbl_void;

__device__ __forceinline__ void gload16(const void* g, void* l) {
  __builtin_amdgcn_global_load_lds((gbl_void*)g, (lds_void*)l, 16, 0, 0);
}

// ---------------------------------------------------------------------------
__global__ __launch_bounds__(256) void convert_a(const float* __restrict__ q,
                                                 _Float16* __restrict__ a) {
  const int stride = gridDim.x * blockDim.x;
  for (int i = blockIdx.x * blockDim.x + threadIdx.x; i < (BT_TOK * DDIM) / 8;
       i += stride) {
    const float4* p = (const float4*)(q + (size_t)i * 8);
    float4 x = p[0], y = p[1];
    half8 h;
    h[0] = (_Float16)x.x; h[1] = (_Float16)x.y;
    h[2] = (_Float16)x.z; h[3] = (_Float16)x.w;
    h[4] = (_Float16)y.x; h[5] = (_Float16)y.y;
    h[6] = (_Float16)y.z; h[7] = (_Float16)y.w;
    *(half8*)(a + (size_t)i * 8) = h;
  }
}

// ---------------------------------------------------------------------------
__global__ __launch_bounds__(256) void build_bt(const float* __restrict__ dw1,
                                                const float* __restrict__ ddw,
                                                _Float16* __restrict__ Bt) {
  __shared__ float tile[64][65];
  const int bn = blockIdx.x % 10, bd = blockIdx.x / 10;
  const int n0 = bn * 64, d0 = bd * 64;
  const int ln = threadIdx.x & 63, rr = threadIdx.x >> 6;
#pragma unroll
  for (int i = 0; i < 16; ++i) {
    int dl = rr + i * 4;
    int d = d0 + dl, n = n0 + ln;
    tile[dl][ln] = (n < 512) ? dw1[d * 512 + n] : ddw[d * 128 + (n - 512)];
  }
  __syncthreads();
#pragma unroll
  for (int i = 0; i < 16; ++i) {
    int nl = rr + i * 4;
    Bt[(size_t)(n0 + nl) * DDIM + d0 + ln] = (_Float16)tile[ln][nl];
  }
}

// ---------------------------------------------------------------------------
__global__ __launch_bounds__(256) void build_qkwT(const float* __restrict__ qkw,
                                                  _Float16* __restrict__ qT) {
  __shared__ float t[128][129];
  const int c = blockIdx.x;
  const float* src = qkw + c * 16384;
  for (int z = threadIdx.x; z < 16384; z += 256) {
    int k = z >> 7, n = z & 127;
    t[k][n] = src[z];
  }
  __syncthreads();
  for (int z = threadIdx.x; z < 16384; z += 256) {
    int n = z >> 7, k = z & 127;
    qT[c * 16384 + z] = (_Float16)t[k][n];
  }
}

// ---------------------------------------------------------------------------
// Fused main kernel. 512 threads (8 waves), BM=128, BN=128, BK=64.
// 3 LDS buffers, depth-2 prefetch, counted vmcnt(4) + raw s_barrier (T3+T4).
// After the K-loop: ntile<4 -> GELU -> Ht in LDS -> second GEMM (x qkwT[c])
// -> rmsnorm -> w1/w2 stores -> (c=1,3) KW outer products.  ntile==4 -> tanh
// -> dd stores. KW diagonal added by kw_diag afterwards.
__global__ __launch_bounds__(512) void gemm_fused(const _Float16* __restrict__ A,
                                                  const _Float16* __restrict__ Bt,
                                                  const _Float16* __restrict__ qT,
                                                  float* __restrict__ out) {
  __shared__ __align__(16) char lds_raw[98304];  // 96 KB
  _Float16* lh = (_Float16*)lds_raw;
  // layout (half idx): Abuf(b) = b*8192 (b<3); Bbuf(b) = 24576 + b*8192
  // epilogue reuse: Ht = [128][136] at 0; stash = float[wave*2048] at 0

  // XCD-bijective swizzle (grid 640 = 8*80)
  int wg = (int)blockIdx.x;
  wg = (wg & 7) * 80 + (wg >> 3);
  const int mtile = wg / 5, ntile = wg - mtile * 5;
  const int m0 = mtile << 7, n0 = ntile << 7;

  const int tid = threadIdx.x;
  const int wave = tid >> 6, lane = tid & 63;
  const int lq = lane >> 4, lc = lane & 15;
  const int wm = (wave >> 1) << 5;  // 0/32/64/96
  const int wn = (wave & 1) << 6;   // 0/64

  // staging: A tile 1024 16B-slots, B same; 2 slots/thread each.
  // slot s -> row=s>>3, kslot=s&7; global source pre-swizzled gs=(s&7)^(row&7),
  // LDS written linearly; reads use kslot = kb^(row&7). [rule #21]
  int aoff[2], boff[2], lb[2];
#pragma unroll
  for (int j = 0; j < 2; ++j) {
    int slot = j * 512 + tid;
    int row = slot >> 3;
    int gs = (slot & 7) ^ (row & 7);
    aoff[j] = (m0 + row) * DDIM + gs * 8;
    boff[j] = (n0 + row) * DDIM + gs * 8;
    lb[j] = j * 4096 + wave * 512;  // wave-uniform LDS base (halfs)
  }

  f32x4 acc[2][4];
#pragma unroll
  for (int i = 0; i < 2; ++i)
#pragma unroll
    for (int j = 0; j < 4; ++j) acc[i][j] = f32x4{0.f, 0.f, 0.f, 0.f};

  auto stage = [&](int kt) {
    int b = kt % 3;
#pragma unroll
    for (int j = 0; j < 2; ++j)
      gload16(A + aoff[j] + kt * 64, lh + b * 8192 + lb[j]);
#pragma unroll
    for (int j = 0; j < 2; ++j)
      gload16(Bt + boff[j] + kt * 64, lh + 24576 + b * 8192 + lb[j]);
  };

  auto compute = [&](int kt) {
    const _Float16* Ab = lh + (kt % 3) * 8192;
    const _Float16* Bb = lh + 24576 + (kt % 3) * 8192;
#pragma unroll
    for (int kk = 0; kk < 2; ++kk) {
      half8 af[2], bf[4];
      const int kb = kk * 4 + lq;
#pragma unroll
      for (int f = 0; f < 2; ++f) {
        int rowA = wm + f * 16 + lc;
        af[f] = *(const half8*)(Ab + rowA * 64 + ((kb ^ (rowA & 7)) << 3));
      }
#pragma unroll
      for (int f = 0; f < 4; ++f) {
        int rowB = wn + f * 16 + lc;
        bf[f] = *(const half8*)(Bb + rowB * 64 + ((kb ^ (rowB & 7)) << 3));
      }
      __builtin_amdgcn_s_setprio(1);
#pragma unroll
      for (int mf = 0; mf < 2; ++mf)
#pragma unroll
        for (int nf = 0; nf < 4; ++nf)
          acc[mf][nf] = __builtin_amdgcn_mfma_f32_16x16x32_f16(
              af[mf], bf[nf], acc[mf][nf], 0, 0, 0);
      __builtin_amdgcn_s_setprio(0);
    }
  };

  // prologue: 2 stages in flight (4 loads each)
  stage(0);
  stage(1);
  for (int t = 0; t < 64; ++t) {
    // wait own stage(t) loads (newest stage may stay in flight), then align
    if (t < 63) {
      asm volatile("s_waitcnt vmcnt(4)" ::: "memory");
    } else {
      asm volatile("s_waitcnt vmcnt(0)" ::: "memory");
    }
    __builtin_amdgcn_s_barrier();
    __builtin_amdgcn_sched_barrier(0);
    if (t < 62) stage(t + 2);  // buf[(t+2)%3] free: last read at t-1, pre-barrier
    compute(t);
  }
  __syncthreads();  // all buf reads done before Ht overwrites A-buffers

  const int c = ntile;
  if (c < 4) {
    // ---- GELU -> Ht[128][136] (fp16) in LDS ----
#pragma unroll
    for (int mf = 0; mf < 2; ++mf)
#pragma unroll
      for (int nf = 0; nf < 4; ++nf)
#pragma unroll
        for (int r = 0; r < 4; ++r) {
          int row = wm + mf * 16 + lq * 4 + r;
          int col = wn + nf * 16 + lc;
          float v = acc[mf][nf][r];
          float g = 0.5f * v * (1.0f + erff(v * 0.70710678118654752f));
          lh[row * 136 + col] = (_Float16)g;
        }
    __syncthreads();  // Ht complete

    // ---- second GEMM: W[tok][n] = Ht x qkwT[c], wave owns 16 tokens ----
    half8 a2[4];
#pragma unroll
    for (int kf = 0; kf < 4; ++kf)
      a2[kf] = *(const half8*)(lh + (wave * 16 + lc) * 136 + kf * 32 + lq * 8);
    f32x4 acc2[8];
#pragma unroll
    for (int nf = 0; nf < 8; ++nf) acc2[nf] = f32x4{0.f, 0.f, 0.f, 0.f};
#pragma unroll
    for (int nf = 0; nf < 8; ++nf) {
      const _Float16* brow = qT + c * 16384 + (nf * 16 + lc) * 128 + lq * 8;
#pragma unroll
      for (int kf = 0; kf < 4; ++kf) {
        half8 b2 = *(const half8*)(brow + kf * 32);
        acc2[nf] = __builtin_amdgcn_mfma_f32_16x16x32_f16(a2[kf], b2, acc2[nf], 0, 0, 0);
      }
    }
    __syncthreads();  // all Ht reads done -> LDS free for stash

    const int w1base = (c >> 1) * OFF_POST_QW1 + (c & 1) * OFF_PRE_KW1;
    const int w2base = w1base + OFF_PRE_QW2;
    const int tok0 = m0 + wave * 16;
    float* st = (float*)lds_raw + wave * 2048;  // [i][16 tok][32 m]

    // acc2[nf][r]: token = tok0 + lq*4 + r, n = nf*16+lc; n = i*32+m
#pragma unroll
    for (int i = 0; i < 4; ++i) {
      float vn0[4], vn1[4];
#pragma unroll
      for (int r = 0; r < 4; ++r) {
        vn0[r] = acc2[2 * i][r];      // m = lc
        vn1[r] = acc2[2 * i + 1][r];  // m = 16+lc
      }
      if (i < 2) {
#pragma unroll
        for (int r = 0; r < 4; ++r) {
          float ss = vn0[r] * vn0[r] + vn1[r] * vn1[r];
          ss += __shfl_xor(ss, 1);
          ss += __shfl_xor(ss, 2);
          ss += __shfl_xor(ss, 4);
          ss += __shfl_xor(ss, 8);
          float sc = rsqrtf(ss * 0.03125f + 1e-6f);
          vn0[r] *= sc;
          vn1[r] *= sc;
        }
      }
      const int basei = ((i < 2) ? w1base : w2base) + (i & 1) * 32;
#pragma unroll
      for (int r = 0; r < 4; ++r) {
        int token = tok0 + lq * 4 + r;
        out[basei + token * 64 + lc] = vn0[r];
        out[basei + token * 64 + 16 + lc] = vn1[r];
        if (c & 1) {  // stash for KW (own wave's region; no barrier needed)
          st[i * 512 + (lq * 4 + r) * 32 + lc] = vn0[r];
          st[i * 512 + (lq * 4 + r) * 32 + 16 + lc] = vn1[r];
        }
      }
    }

    if (c & 1) {  // KW outer products (diag added later by kw_diag)
      const int pp = c >> 1;  // c=1 -> pre(0), c=3 -> post(1)
#pragma unroll 8
      for (int it = 0; it < 64; ++it) {
        int slot = it * 64 + lane;           // f32x4 slots, 4096 per wave
        int tl = slot >> 8;
        int mrow = (slot >> 3) & 31, n4 = (slot & 7) << 2;
        f32x4 s2 = *(const f32x4*)(st + 2 * 512 + tl * 32 + n4);
        f32x4 s3 = *(const f32x4*)(st + 3 * 512 + tl * 32 + n4);
        float a0 = st[0 * 512 + tl * 32 + mrow];
        float a1 = st[1 * 512 + tl * 32 + mrow];
        f32x4 v = a0 * s2 + a1 * s3;
        *(f32x4*)(&out[OFF_KW + (size_t)(tok0 + tl) * 2048 + pp * 1024 +
                       mrow * 32 + n4]) = v;
      }
    }
  } else {
    // ---- dd block: tanh -> 4 dd outputs ----
#pragma unroll
    for (int mf = 0; mf < 2; ++mf)
#pragma unroll
      for (int nf = 0; nf < 4; ++nf) {
        int j = wn + nf * 16 + lc;  // 0..127
        int t = j >> 5;             // 0:pre_q 1:pre_k 2:post_q 3:post_k
        int base = (t & 2) ? ((t & 1) ? OFF_POST_KDD : OFF_POST_QDD)
                           : ((t & 1) ? OFF_PRE_KDD : OFF_PRE_QDD);
        int row0 = m0 + wm + mf * 16 + lq * 4;
#pragma unroll
        for (int r = 0; r < 4; ++r)
          out[base + (row0 + r) * 32 + (j & 31)] = tanhf(acc[mf][nf][r]);
      }
  }
}

// ---------------------------------------------------------------------------
// KW[tok][pp][m][m] += kdd[pp][tok][m]
__global__ __launch_bounds__(256) void kw_diag(float* __restrict__ out) {
  int idx = blockIdx.x * 256 + threadIdx.x;  // 2*16384*32 = 1M
  int tok = idx >> 6;
  int pp = (idx >> 5) & 1, m = idx & 31;
  float kdd = out[(pp ? OFF_POST_KDD : OFF_PRE_KDD) + tok * 32 + m];
  out[OFF_KW + (size_t)tok * 2048 + pp * 1024 + m * 33] += kdd;
}

// ---------------------------------------------------------------------------
extern "C" void kernel_launch(void* const* d_in, const int* in_sizes, int n_in,
                              void* d_out, int out_size, void* d_ws, size_t ws_size,
                              hipStream_t stream) {
  const float* q   = (const float*)d_in[0];
  const float* dw1 = (const float*)d_in[1];
  const float* qkw = (const float*)d_in[2];
  const float* ddw = (const float*)d_in[3];
  float* out = (float*)d_out;

  _Float16* Ah = (_Float16*)d_ws;             // 128 MiB
  _Float16* Bt = Ah + (size_t)BT_TOK * DDIM;  // 5 MiB
  _Float16* qT = Bt + (size_t)640 * DDIM;     // 128 KiB

  convert_a<<<2048, 256, 0, stream>>>(q, Ah);
  build_bt<<<640, 256, 0, stream>>>(dw1, ddw, Bt);
  build_qkwT<<<4, 256, 0, stream>>>(qkw, qT);
  gemm_fused<<<640, 512, 0, stream>>>(Ah, Bt, qT, out);
  kw_diag<<<4096, 256, 0, stream>>>(out);
}